// Round 1
// 732.271 us; speedup vs baseline: 1.0614x; 1.0614x over previous
//
#include <hip/hip_runtime.h>
#include <math.h>

constexpr int DH = 256;
#define EPSV 1e-5f

typedef __bf16 bf16_t;
typedef bf16_t bf16x8 __attribute__((ext_vector_type(8)));
typedef float floatx4 __attribute__((ext_vector_type(4)));

// fast gelu: tanh via hardware exp (v_exp_f32)
__device__ __forceinline__ float gelu_f(float x) {
    float x3 = x * x * x;
    float z = 0.7978845608028654f * (x + 0.044715f * x3);
    float e = __expf(2.0f * z);
    float t = 1.0f - 2.0f / (e + 1.0f);
    return 0.5f * x * (1.0f + t);
}

__device__ __forceinline__ unsigned short f2bf(float x) {
    unsigned int u = __float_as_uint(x);
    u += 0x7FFFu + ((u >> 16) & 1u);
    return (unsigned short)(u >> 16);
}

__device__ __forceinline__ float bf2f(unsigned short u) {
    return __uint_as_float(((unsigned int)u) << 16);
}

__device__ __forceinline__ void addbf8(float* acc, uint4 u) {
    const unsigned short* p = (const unsigned short*)&u;
#pragma unroll
    for (int k = 0; k < 8; k++) acc[k] += bf2f(p[k]);
}

__device__ __forceinline__ void addbf4(float* acc, ushort4 u) {
    acc[0] += bf2f(u.x);
    acc[1] += bf2f(u.y);
    acc[2] += bf2f(u.z);
    acc[3] += bf2f(u.w);
}

// ---------------- CSR build ----------------

__global__ void count_edges_k(const int* __restrict__ dst, int* __restrict__ cnt, int e, int n) {
    int i = blockIdx.x * 256 + threadIdx.x;
    if (i < e) {
        int d = dst[i];
        d = (d < 0) ? 0 : ((d >= n) ? n - 1 : d);
        atomicAdd(&cnt[d], 1);
    }
}

__global__ void deg_k(const int* __restrict__ cnt, float* __restrict__ isd,
                      float* __restrict__ sdeg, int n) {
    int i = blockIdx.x * 256 + threadIdx.x;
    if (i < n) {
        float d = (float)cnt[i] + 1.0f;   // +1 self loop
        float r = rsqrtf(d);
        isd[i] = r;
        sdeg[i] = d * r;                  // sqrt(d)
    }
}

__global__ __launch_bounds__(256) void scan1_k(const int* __restrict__ cnt,
                                               int* __restrict__ bsum, int n) {
    __shared__ int red[256];
    int t = threadIdx.x;
    int base = blockIdx.x * 1024 + t * 4;
    int s = 0;
    if (base + 3 < n) {
        int4 v = *(const int4*)&cnt[base];
        s = v.x + v.y + v.z + v.w;
    } else {
#pragma unroll
        for (int k = 0; k < 4; k++) {
            int idx = base + k;
            if (idx < n) s += cnt[idx];
        }
    }
    red[t] = s;
    __syncthreads();
    for (int off = 128; off > 0; off >>= 1) {
        if (t < off) red[t] += red[t + off];
        __syncthreads();
    }
    if (t == 0) bsum[blockIdx.x] = red[0];
}

__global__ __launch_bounds__(256) void scan2_k(const int* __restrict__ bsum,
                                               int* __restrict__ boff, int G,
                                               int* __restrict__ row_end, int E) {
    __shared__ int part[256];
    int t = threadIdx.x;
    int own = (t < G) ? bsum[t] : 0;
    part[t] = own;
    __syncthreads();
    for (int off = 1; off < 256; off <<= 1) {
        int v = (t >= off) ? part[t - off] : 0;
        __syncthreads();
        part[t] += v;
        __syncthreads();
    }
    if (t < G) boff[t] = part[t] - own;   // exclusive
    if (t == 0) row_end[0] = E;           // row_start[n]
}

__global__ __launch_bounds__(256) void scan3_k(const int* __restrict__ cnt,
                                               const int* __restrict__ boff,
                                               int* __restrict__ row_start,
                                               int* __restrict__ cursor, int n) {
    __shared__ int part[256];
    int t = threadIdx.x;
    int base = blockIdx.x * 1024 + t * 4;
    int v[4];
    if (base + 3 < n) {
        int4 q = *(const int4*)&cnt[base];
        v[0] = q.x; v[1] = q.y; v[2] = q.z; v[3] = q.w;
    } else {
#pragma unroll
        for (int k = 0; k < 4; k++) v[k] = (base + k < n) ? cnt[base + k] : 0;
    }
    int s = v[0] + v[1] + v[2] + v[3];
    int own = s;
    part[t] = s;
    __syncthreads();
    for (int off = 1; off < 256; off <<= 1) {
        int q = (t >= off) ? part[t - off] : 0;
        __syncthreads();
        part[t] += q;
        __syncthreads();
    }
    int run = boff[blockIdx.x] + part[t] - own;
#pragma unroll
    for (int k = 0; k < 4; k++) {
        int idx = base + k;
        if (idx < n) {
            row_start[idx] = run;
            cursor[idx] = run;
            run += v[k];
        }
    }
}

__global__ void scatter_edges_k(const int* __restrict__ src, const int* __restrict__ dst,
                                int* __restrict__ cursor, int* __restrict__ esrc, int e, int n) {
    int i = blockIdx.x * 256 + threadIdx.x;
    if (i < e) {
        int d = dst[i];
        d = (d < 0) ? 0 : ((d >= n) ? n - 1 : d);
        int s = src[i];
        s = (s < 0) ? 0 : ((s >= n) ? n - 1 : s);
        int pos = atomicAdd(&cursor[d], 1);
        esrc[pos] = s;
    }
}

// ---------------- bf16 conversion ----------------

__global__ void f2bf_xsc_k(const float* __restrict__ x, const float* __restrict__ isd,
                           unsigned short* __restrict__ xsc, int n4) {
    int i4 = blockIdx.x * 256 + threadIdx.x;
    if (i4 < n4) {
        float si = isd[i4 >> 5];
        float4 v = ((const float4*)x)[i4];
        ushort4 o;
        o.x = f2bf(si * v.x); o.y = f2bf(si * v.y);
        o.z = f2bf(si * v.z); o.w = f2bf(si * v.w);
        ((ushort4*)xsc)[i4] = o;
    }
}

__global__ void wt_all_k(const float* __restrict__ s0, const float* __restrict__ s1,
                         const float* __restrict__ s2, const float* __restrict__ s3,
                         const float* __restrict__ s4, const float* __restrict__ s5,
                         unsigned short* __restrict__ d0, unsigned short* __restrict__ d1,
                         unsigned short* __restrict__ d2, unsigned short* __restrict__ d3,
                         unsigned short* __restrict__ d4, unsigned short* __restrict__ d5) {
    int y = blockIdx.y, k = blockIdx.x, nn = threadIdx.x;
    const float* S;
    unsigned short* D;
    int K;
    switch (y) {
        case 0: S = s0; D = d0; K = 128; break;
        case 1: S = s1; D = d1; K = 128; break;
        case 2: S = s2; D = d2; K = 256; break;
        case 3: S = s3; D = d3; K = 256; break;
        case 4: S = s4; D = d4; K = 256; break;
        default: S = s5; D = d5; K = 256; break;
    }
    if (k >= K) return;
    D[(size_t)nn * K + k] = f2bf(S[(size_t)k * 256 + nn]);
}

// ---------------- bf16 MFMA GEMM: full-width 512-thread blocks, B in VGPRs ------------
// C[M][256] = A[M][K] @ W[K][256]. Block = 512 threads = 8 waves covering a 32-row x
// 256-col tile: wave = (wm in 0..1 row-group of 16) x (wn in 0..3 col-quarter).
// Each wave holds its quarter's B fragments in VGPRs (loaded once; persistent blocks,
// grid-stride over row tiles). The 4 col-quarter waves of a row-group issue IDENTICAL
// A loads -> served by the CU's L1 (16KB tile) => A leaves fabric exactly once.
// mfma(bfrag, afrag, acc): thread owns C-row gr, 4-consecutive-col groups.
// SPRE: v *= rowscale before bias.  SCALE: v *= rowscale at end.
// STATS: accumulate per-column sum/sumsq of v (f32, pre-bf16-round) -> pstats[block][512]
//        (shfl butterfly over the 16 l15-lanes sharing cols, LDS combine over wm).
// HEAD:  no C store; per-row dot with hw (f32), shfl over quad lanes, atomicAdd hout[gr].

template <int K, bool BIAS, bool GELU_, bool SPRE, bool SCALE, bool STATS, bool HEAD>
__global__ __launch_bounds__(512) void gemm_bf_k(const unsigned short* __restrict__ A,
                                                 const unsigned short* __restrict__ Wt,
                                                 const float* __restrict__ bias,
                                                 const float* __restrict__ rowscale,
                                                 unsigned short* __restrict__ CB,
                                                 int M,
                                                 const float* __restrict__ hw,
                                                 const float* __restrict__ hb,
                                                 float* __restrict__ hout,
                                                 float* __restrict__ pstats) {
    constexpr int CH = K / 32;
    const int lane = threadIdx.x & 63;
    const int wave = threadIdx.x >> 6;
    const int wm = wave & 1;               // row group (16 rows)
    const int wn = wave >> 1;              // col quarter
    const int l15 = lane & 15;
    const int quad = lane >> 4;

    bf16x8 bfr[CH][4];
#pragma unroll
    for (int c = 0; c < CH; c++)
#pragma unroll
        for (int j = 0; j < 4; j++) {
            int col = wn * 64 + j * 16 + l15;
            bfr[c][j] = *(const bf16x8*)&Wt[(size_t)col * K + c * 32 + quad * 8];
        }

    float hwv[16];
    if (HEAD) {
#pragma unroll
        for (int j = 0; j < 4; j++) {
            float4 w4 = *(const float4*)&hw[wn * 64 + j * 16 + quad * 4];
            hwv[j * 4 + 0] = w4.x; hwv[j * 4 + 1] = w4.y;
            hwv[j * 4 + 2] = w4.z; hwv[j * 4 + 3] = w4.w;
        }
    }
    float sacc[STATS ? 16 : 1], s2acc[STATS ? 16 : 1];
    if (STATS) {
#pragma unroll
        for (int k = 0; k < 16; k++) { sacc[k] = 0.f; s2acc[k] = 0.f; }
    }

    const int nTiles = (M + 31) >> 5;
    for (int rt = blockIdx.x; rt < nTiles; rt += gridDim.x) {
        int gr = rt * 32 + wm * 16 + l15;
        int grc = (gr < M) ? gr : (M - 1);
        const unsigned short* ap = &A[(size_t)grc * K + quad * 8];

        bf16x8 a[CH];
#pragma unroll
        for (int c = 0; c < CH; c++) a[c] = *(const bf16x8*)(ap + c * 32);

        floatx4 acc[4];
#pragma unroll
        for (int j = 0; j < 4; j++) acc[j] = (floatx4){0.f, 0.f, 0.f, 0.f};
#pragma unroll
        for (int c = 0; c < CH; c++)
#pragma unroll
            for (int j = 0; j < 4; j++)
                acc[j] = __builtin_amdgcn_mfma_f32_16x16x32_bf16(bfr[c][j], a[c], acc[j], 0, 0, 0);

        if (gr < M) {
            float rs = (SPRE || SCALE) ? rowscale[gr] : 1.0f;
            float hpart = 0.f;
#pragma unroll
            for (int j = 0; j < 4; j++) {
                int gc0 = wn * 64 + j * 16 + quad * 4;       // 4 consecutive C-cols
                float4 bv;
                if (BIAS) bv = *(const float4*)&bias[gc0];
                float v0 = acc[j][0], v1 = acc[j][1], v2 = acc[j][2], v3 = acc[j][3];
                if (SPRE) { v0 *= rs; v1 *= rs; v2 *= rs; v3 *= rs; }
                if (BIAS) { v0 += bv.x; v1 += bv.y; v2 += bv.z; v3 += bv.w; }
                if (GELU_) { v0 = gelu_f(v0); v1 = gelu_f(v1); v2 = gelu_f(v2); v3 = gelu_f(v3); }
                if (SCALE) { v0 *= rs; v1 *= rs; v2 *= rs; v3 *= rs; }
                if (STATS) {
                    sacc[j * 4 + 0] += v0; s2acc[j * 4 + 0] += v0 * v0;
                    sacc[j * 4 + 1] += v1; s2acc[j * 4 + 1] += v1 * v1;
                    sacc[j * 4 + 2] += v2; s2acc[j * 4 + 2] += v2 * v2;
                    sacc[j * 4 + 3] += v3; s2acc[j * 4 + 3] += v3 * v3;
                }
                if (HEAD) {
                    hpart += v0 * hwv[j * 4 + 0] + v1 * hwv[j * 4 + 1]
                           + v2 * hwv[j * 4 + 2] + v3 * hwv[j * 4 + 3];
                } else {
                    ushort4 o;
                    o.x = f2bf(v0); o.y = f2bf(v1); o.z = f2bf(v2); o.w = f2bf(v3);
                    *(ushort4*)&CB[(size_t)gr * DH + gc0] = o;
                }
            }
            if (HEAD) {
                // lanes sharing a row are {l15 + 16q}: same l15 => same gr (no
                // divergence across partners since M rows never split a 16-group)
                hpart += __shfl_xor(hpart, 16, 64);
                hpart += __shfl_xor(hpart, 32, 64);
                if (quad == 0)
                    atomicAdd(&hout[gr], hpart + (wn == 0 ? hb[0] : 0.f));
            }
        }
    }

    if (STATS) {
        // butterfly over the 16 lanes (l15) that share this thread's 16 columns
#pragma unroll
        for (int m = 1; m < 16; m <<= 1) {
#pragma unroll
            for (int k = 0; k < 16; k++) {
                sacc[k] += __shfl_xor(sacc[k], m, 64);
                s2acc[k] += __shfl_xor(s2acc[k], m, 64);
            }
        }
        __shared__ float st[STATS ? 1024 : 1];
        if (l15 == 0) {
#pragma unroll
            for (int j = 0; j < 4; j++)
#pragma unroll
                for (int k = 0; k < 4; k++) {
                    int col = wn * 64 + j * 16 + quad * 4 + k;
                    st[wm * 512 + col] = sacc[j * 4 + k];
                    st[wm * 512 + 256 + col] = s2acc[j * 4 + k];
                }
        }
        __syncthreads();
        int t = threadIdx.x;
        pstats[(size_t)blockIdx.x * 512 + t] = st[t] + st[512 + t];
    }
}

// ---------------- layer-0 aggregation on xsc ----------------

__global__ __launch_bounds__(256) void agg_x_k(const unsigned short* __restrict__ xsc,
                                               const int* __restrict__ esrc,
                                               const int* __restrict__ row_start,
                                               const float* __restrict__ isd,
                                               unsigned short* __restrict__ out, int n) {
    int half = threadIdx.x >> 5;
    int sub = threadIdx.x & 31;
    int i = blockIdx.x * 8 + half;
    if (i >= n) return;
    int beg = row_start[i], end = row_start[i + 1];
    int c = sub * 4;
    float acc[4] = {0.f, 0.f, 0.f, 0.f};
    addbf4(acc, *(const ushort4*)&xsc[(size_t)i * 128 + c]);   // self
    int e = beg;
    for (; e + 15 < end; e += 16) {
        int s[16];
        ushort4 u[16];
#pragma unroll
        for (int k = 0; k < 16; k++) s[k] = esrc[e + k];
#pragma unroll
        for (int k = 0; k < 16; k++) u[k] = *(const ushort4*)&xsc[(size_t)s[k] * 128 + c];
#pragma unroll
        for (int k = 0; k < 16; k++) addbf4(acc, u[k]);
    }
    for (; e + 7 < end; e += 8) {
        int s[8];
        ushort4 u[8];
#pragma unroll
        for (int k = 0; k < 8; k++) s[k] = esrc[e + k];
#pragma unroll
        for (int k = 0; k < 8; k++) u[k] = *(const ushort4*)&xsc[(size_t)s[k] * 128 + c];
#pragma unroll
        for (int k = 0; k < 8; k++) addbf4(acc, u[k]);
    }
    for (; e + 1 < end; e += 2) {
        int s0 = esrc[e], s1 = esrc[e + 1];
        ushort4 a = *(const ushort4*)&xsc[(size_t)s0 * 128 + c];
        ushort4 b = *(const ushort4*)&xsc[(size_t)s1 * 128 + c];
        addbf4(acc, a);
        addbf4(acc, b);
    }
    if (e < end)
        addbf4(acc, *(const ushort4*)&xsc[(size_t)esrc[e] * 128 + c]);
    float si = isd[i];
    ushort4 o;
    o.x = f2bf(si * acc[0]); o.y = f2bf(si * acc[1]);
    o.z = f2bf(si * acc[2]); o.w = f2bf(si * acc[3]);
    *(ushort4*)&out[(size_t)i * 128 + c] = o;
}

// ---------------- layers 1,2 aggregation + BN partials ----------------

__global__ __launch_bounds__(256) void agg_h_k(const unsigned short* __restrict__ hws,
                                               const int* __restrict__ esrc,
                                               const int* __restrict__ row_start,
                                               const float* __restrict__ isd,
                                               const float* __restrict__ bias,
                                               unsigned short* __restrict__ out,
                                               float* __restrict__ pbuf, int n) {
    __shared__ float ls[2048];
    int t = threadIdx.x;
    int half = t >> 5;
    int sub = t & 31;
    int c = sub * 8;
    int i = blockIdx.x * 8 + half;

    float o[8] = {0.f, 0.f, 0.f, 0.f, 0.f, 0.f, 0.f, 0.f};
    if (i < n) {
        int beg = row_start[i], end = row_start[i + 1];
        float acc[8] = {0.f, 0.f, 0.f, 0.f, 0.f, 0.f, 0.f, 0.f};
        addbf8(acc, *(const uint4*)&hws[(size_t)i * DH + c]);   // self
        int e = beg;
        for (; e + 15 < end; e += 16) {
            int s[16];
            uint4 u[16];
#pragma unroll
            for (int k = 0; k < 16; k++) s[k] = esrc[e + k];
#pragma unroll
            for (int k = 0; k < 16; k++) u[k] = *(const uint4*)&hws[(size_t)s[k] * DH + c];
#pragma unroll
            for (int k = 0; k < 16; k++) addbf8(acc, u[k]);
        }
        for (; e + 7 < end; e += 8) {
            int s[8];
            uint4 u[8];
#pragma unroll
            for (int k = 0; k < 8; k++) s[k] = esrc[e + k];
#pragma unroll
            for (int k = 0; k < 8; k++) u[k] = *(const uint4*)&hws[(size_t)s[k] * DH + c];
#pragma unroll
            for (int k = 0; k < 8; k++) addbf8(acc, u[k]);
        }
        for (; e + 1 < end; e += 2) {
            int s0 = esrc[e], s1 = esrc[e + 1];
            uint4 a = *(const uint4*)&hws[(size_t)s0 * DH + c];
            uint4 b = *(const uint4*)&hws[(size_t)s1 * DH + c];
            addbf8(acc, a);
            addbf8(acc, b);
        }
        if (e < end)
            addbf8(acc, *(const uint4*)&hws[(size_t)esrc[e] * DH + c]);
        float si = isd[i];
        float4 b0 = *(const float4*)&bias[c];
        float4 b1 = *(const float4*)&bias[c + 4];
        o[0] = si * acc[0] + b0.x; o[1] = si * acc[1] + b0.y;
        o[2] = si * acc[2] + b0.z; o[3] = si * acc[3] + b0.w;
        o[4] = si * acc[4] + b1.x; o[5] = si * acc[5] + b1.y;
        o[6] = si * acc[6] + b1.z; o[7] = si * acc[7] + b1.w;
        ushort4 q0, q1;
        q0.x = f2bf(o[0]); q0.y = f2bf(o[1]); q0.z = f2bf(o[2]); q0.w = f2bf(o[3]);
        q1.x = f2bf(o[4]); q1.y = f2bf(o[5]); q1.z = f2bf(o[6]); q1.w = f2bf(o[7]);
        *(ushort4*)&out[(size_t)i * DH + c] = q0;
        *(ushort4*)&out[(size_t)i * DH + c + 4] = q1;
    }
    *(float4*)&ls[half * 256 + c]     = make_float4(o[0], o[1], o[2], o[3]);
    *(float4*)&ls[half * 256 + c + 4] = make_float4(o[4], o[5], o[6], o[7]);
    __syncthreads();
    float s = 0.f, s2 = 0.f;
#pragma unroll
    for (int h = 0; h < 8; h++) {
        float v = ls[h * 256 + t];
        s += v;
        s2 += v * v;
    }
    pbuf[(size_t)blockIdx.x * 512 + t] = s;
    pbuf[(size_t)blockIdx.x * 512 + 256 + t] = s2;
}

// reduce pbuf[nb][512] -> pbuf2[64][512]
__global__ __launch_bounds__(256) void bn_reduce_k(const float* __restrict__ pbuf,
                                                   float* __restrict__ pbuf2, int nb) {
    int t = threadIdx.x;
    float s = 0.f, s2 = 0.f;
    for (int r = blockIdx.x; r < nb; r += gridDim.x) {
        s += pbuf[(size_t)r * 512 + t];
        s2 += pbuf[(size_t)r * 512 + 256 + t];
    }
    pbuf2[(size_t)blockIdx.x * 512 + t] = s;
    pbuf2[(size_t)blockIdx.x * 512 + 256 + t] = s2;
}

__global__ void bn_finalize_k(const float* __restrict__ pbuf2, int nrows,
                              const float* __restrict__ g, const float* __restrict__ b,
                              float* __restrict__ ss, float inv_n) {
    int j = threadIdx.x;
    float s = 0.f, s2 = 0.f;
    for (int r = 0; r < nrows; r++) {
        s += pbuf2[(size_t)r * 512 + j];
        s2 += pbuf2[(size_t)r * 512 + 256 + j];
    }
    float mu = s * inv_n;
    float var = s2 * inv_n - mu * mu;
    float sc = g[j] * rsqrtf(var + EPSV);
    ss[j] = sc;
    ss[DH + j] = b[j] - mu * sc;
}

__global__ __launch_bounds__(256) void bn_act_res_k(const unsigned short* __restrict__ gcn_bf,
                                                    const float* __restrict__ ss,
                                                    const unsigned short* __restrict__ resid_bf,
                                                    unsigned short* __restrict__ out_bf, int n) {
    size_t idx = ((size_t)blockIdx.x * 256 + threadIdx.x) * 8;
    if (idx >= (size_t)n * DH) return;
    int j = (int)(idx & (DH - 1));
    uint4 gv = *(const uint4*)&gcn_bf[idx];
    uint4 rv = *(const uint4*)&resid_bf[idx];
    const unsigned short* gp = (const unsigned short*)&gv;
    const unsigned short* rp = (const unsigned short*)&rv;
    float4 sc0 = *(const float4*)&ss[j];
    float4 sc1 = *(const float4*)&ss[j + 4];
    float4 sh0 = *(const float4*)&ss[DH + j];
    float4 sh1 = *(const float4*)&ss[DH + j + 4];
    float scv[8] = {sc0.x, sc0.y, sc0.z, sc0.w, sc1.x, sc1.y, sc1.z, sc1.w};
    float shv[8] = {sh0.x, sh0.y, sh0.z, sh0.w, sh1.x, sh1.y, sh1.z, sh1.w};
    unsigned short ob[8];
#pragma unroll
    for (int k = 0; k < 8; k++) {
        float v = bf2f(gp[k]) * scv[k] + shv[k];
        ob[k] = f2bf(gelu_f(v) + bf2f(rp[k]));
    }
    *(uint4*)&out_bf[idx] = *(const uint4*)ob;
}

// ---------------- launch ----------------

extern "C" void kernel_launch(void* const* d_in, const int* in_sizes, int n_in,
                              void* d_out, int out_size, void* d_ws, size_t ws_size,
                              hipStream_t stream) {
    const float* x = (const float*)d_in[0];
    const int* eidx = (const int*)d_in[1];       // int64 in ref -> int32 on device
    const float* conv_w0 = (const float*)d_in[3];
    const float* conv_b0 = (const float*)d_in[4];
    const float* conv_w1 = (const float*)d_in[5];
    const float* conv_b1 = (const float*)d_in[6];
    const float* conv_w2 = (const float*)d_in[7];
    const float* conv_b2 = (const float*)d_in[8];
    const float* bn_g0 = (const float*)d_in[9];
    const float* bn_b0 = (const float*)d_in[10];
    const float* bn_g1 = (const float*)d_in[11];
    const float* bn_b1 = (const float*)d_in[12];
    const float* bn_g2 = (const float*)d_in[13];
    const float* bn_b2 = (const float*)d_in[14];
    const float* proj_w = (const float*)d_in[15];
    const float* proj_b = (const float*)d_in[16];
    const float* lin_w0 = (const float*)d_in[17];
    const float* lin_b0 = (const float*)d_in[18];
    const float* lin_w1 = (const float*)d_in[19];
    const float* lin_b1 = (const float*)d_in[20];
    const float* head_w = (const float*)d_in[21];
    const float* head_b = (const float*)d_in[22];

    const int N = in_sizes[2];
    const int E = in_sizes[1] / 2;
    const int* esrc_in = eidx;
    const int* edst_in = eidx + E;

    char* ws = (char*)d_ws;
    auto alloc = [&](size_t b) -> char* {
        char* p = ws;
        ws += (b + 255) & ~(size_t)255;
        return p;
    };
    unsigned short* h1_bf = (unsigned short*)alloc((size_t)N * DH * 2);
    unsigned short* h2_bf = (unsigned short*)alloc((size_t)N * DH * 2);
    unsigned short* hw_bf = (unsigned short*)alloc((size_t)N * DH * 2);
    unsigned short* pj_bf = (unsigned short*)alloc((size_t)N * DH * 2);
    unsigned short* gcn_bf = (unsigned short*)alloc((size_t)N * DH * 2);
    unsigned short* xsc = (unsigned short*)alloc((size_t)N * 128 * 2);
    unsigned short* axs = (unsigned short*)alloc((size_t)N * 128 * 2);   // S·x ; later pbuf
    float* pbuf2 = (float*)alloc((size_t)256 * 512 * 4);
    unsigned short* w0t = (unsigned short*)alloc((size_t)256 * 128 * 2);
    unsigned short* pjt = (unsigned short*)alloc((size_t)256 * 128 * 2);
    unsigned short* w1t = (unsigned short*)alloc((size_t)256 * 256 * 2);
    unsigned short* w2t = (unsigned short*)alloc((size_t)256 * 256 * 2);
    unsigned short* l0t = (unsigned short*)alloc((size_t)256 * 256 * 2);
    unsigned short* l1t = (unsigned short*)alloc((size_t)256 * 256 * 2);
    int* cnt = (int*)alloc((size_t)N * 4);
    int* row_start = (int*)alloc((size_t)(N + 1) * 4);
    int* cursor = (int*)alloc((size_t)N * 4);
    int* esrc = (int*)alloc((size_t)E * 4);
    float* isd = (float*)alloc((size_t)N * 4);
    float* sdeg = (float*)alloc((size_t)N * 4);
    float* ss = (float*)alloc(2 * DH * 4);
    int* bsum = (int*)alloc(256 * 4);
    int* boff = (int*)alloc(256 * 4);

    // pbuf (agg_h BN partials, gHalf*512 floats = 12.8MB) aliases axs (dead after conv0)
    float* pbuf = (float*)axs;

    const int gE = (E + 255) / 256;
    const int gN = (N + 255) / 256;
    const int gHalf = (N + 7) / 8;
    const int gElem = (int)(((size_t)N * DH / 8 + 255) / 256);
    const int gScan = (N + 1023) / 1024;
    const int gGemm = 256;                       // persistent full-width blocks (1/CU)
    const int gGemmW = 512;                      // K=128 plain gemm: ~116 VGPR -> 2 blocks/CU
    const float inv_n = 1.0f / (float)N;

    // CSR build
    hipMemsetAsync(cnt, 0, (size_t)N * 4, stream);
    hipMemsetAsync(d_out, 0, (size_t)N * 4, stream);   // head accumulates via atomicAdd
    count_edges_k<<<gE, 256, 0, stream>>>(edst_in, cnt, E, N);
    deg_k<<<gN, 256, 0, stream>>>(cnt, isd, sdeg, N);
    scan1_k<<<gScan, 256, 0, stream>>>(cnt, bsum, N);
    scan2_k<<<1, 256, 0, stream>>>(bsum, boff, gScan, &row_start[N], E);
    scan3_k<<<gScan, 256, 0, stream>>>(cnt, boff, row_start, cursor, N);
    scatter_edges_k<<<gE, 256, 0, stream>>>(esrc_in, edst_in, cursor, esrc, E, N);

    // weights + xsc = isd*x (bf16)
    wt_all_k<<<dim3(256, 6), 256, 0, stream>>>(conv_w0, proj_w, conv_w1, conv_w2, lin_w0, lin_w1,
                                               w0t, pjt, w1t, w2t, l0t, l1t);
    f2bf_xsc_k<<<(N * 128 / 4 + 255) / 256, 256, 0, stream>>>(x, isd, xsc, N * 128 / 4);

    // ---- layer 0 ----
    agg_x_k<<<gHalf, 256, 0, stream>>>(xsc, esrc, row_start, isd, axs, N);
    // proj: (xsc @ pjt) * sdeg + proj_b   (= x @ proj_w + proj_b, since xsc = isd*x)
    gemm_bf_k<128, true, false, true, false, false, false><<<gGemmW, 512, 0, stream>>>(
        xsc, pjt, proj_b, sdeg, pj_bf, N, nullptr, nullptr, nullptr, nullptr);
    // conv0 GEMM with fused BN stats (f32, pre-round) -> pbuf2[0..gGemm)
    gemm_bf_k<128, true, false, false, false, true, false><<<gGemm, 512, 0, stream>>>(
        axs, w0t, conv_b0, nullptr, gcn_bf, N, nullptr, nullptr, nullptr, pbuf2);
    bn_finalize_k<<<1, DH, 0, stream>>>(pbuf2, gGemm, bn_g0, bn_b0, ss, inv_n);
    bn_act_res_k<<<gElem, 256, 0, stream>>>(gcn_bf, ss, pj_bf, h1_bf, N);

    // ---- layer 1 ----
    gemm_bf_k<256, false, false, false, true, false, false><<<gGemm, 512, 0, stream>>>(
        h1_bf, w1t, nullptr, isd, hw_bf, N, nullptr, nullptr, nullptr, nullptr);
    agg_h_k<<<gHalf, 256, 0, stream>>>(hw_bf, esrc, row_start, isd, conv_b1, gcn_bf, pbuf, N);
    bn_reduce_k<<<64, 256, 0, stream>>>(pbuf, pbuf2, gHalf);
    bn_finalize_k<<<1, DH, 0, stream>>>(pbuf2, 64, bn_g1, bn_b1, ss, inv_n);
    bn_act_res_k<<<gElem, 256, 0, stream>>>(gcn_bf, ss, h1_bf, h2_bf, N);

    // ---- layer 2 ----
    gemm_bf_k<256, false, false, false, true, false, false><<<gGemm, 512, 0, stream>>>(
        h2_bf, w2t, nullptr, isd, hw_bf, N, nullptr, nullptr, nullptr, nullptr);
    agg_h_k<<<gHalf, 256, 0, stream>>>(hw_bf, esrc, row_start, isd, conv_b2, gcn_bf, pbuf, N);
    bn_reduce_k<<<64, 256, 0, stream>>>(pbuf, pbuf2, gHalf);
    bn_finalize_k<<<1, DH, 0, stream>>>(pbuf2, 64, bn_g2, bn_b2, ss, inv_n);
    bn_act_res_k<<<gElem, 256, 0, stream>>>(gcn_bf, ss, h2_bf, h1_bf, N);   // h3

    // ---- MLP + head ----
    gemm_bf_k<256, true, true, false, false, false, false><<<gGemm, 512, 0, stream>>>(
        h1_bf, l0t, lin_b0, nullptr, h2_bf, N, nullptr, nullptr, nullptr, nullptr);
    // final GEMM with fused head: no C materialization, atomic row-dot into d_out
    gemm_bf_k<256, true, true, false, false, false, true><<<gGemm, 512, 0, stream>>>(
        h2_bf, l1t, lin_b1, nullptr, nullptr, N, head_w, head_b, (float*)d_out, nullptr);
}

// Round 2
// 715.116 us; speedup vs baseline: 1.0869x; 1.0240x over previous
//
#include <hip/hip_runtime.h>
#include <math.h>

constexpr int DH = 256;
#define EPSV 1e-5f

typedef __bf16 bf16_t;
typedef bf16_t bf16x8 __attribute__((ext_vector_type(8)));
typedef float floatx4 __attribute__((ext_vector_type(4)));

// fast gelu: tanh via hardware exp (v_exp_f32)
__device__ __forceinline__ float gelu_f(float x) {
    float x3 = x * x * x;
    float z = 0.7978845608028654f * (x + 0.044715f * x3);
    float e = __expf(2.0f * z);
    float t = 1.0f - 2.0f / (e + 1.0f);
    return 0.5f * x * (1.0f + t);
}

__device__ __forceinline__ unsigned short f2bf(float x) {
    unsigned int u = __float_as_uint(x);
    u += 0x7FFFu + ((u >> 16) & 1u);
    return (unsigned short)(u >> 16);
}

__device__ __forceinline__ float bf2f(unsigned short u) {
    return __uint_as_float(((unsigned int)u) << 16);
}

__device__ __forceinline__ void addbf8(float* acc, uint4 u) {
    const unsigned short* p = (const unsigned short*)&u;
#pragma unroll
    for (int k = 0; k < 8; k++) acc[k] += bf2f(p[k]);
}

__device__ __forceinline__ void addbf4(float* acc, ushort4 u) {
    acc[0] += bf2f(u.x);
    acc[1] += bf2f(u.y);
    acc[2] += bf2f(u.z);
    acc[3] += bf2f(u.w);
}

// ---------------- CSR build ----------------

__global__ void count_edges_k(const int* __restrict__ dst, int* __restrict__ cnt, int e, int n) {
    int i = blockIdx.x * 256 + threadIdx.x;
    if (i < e) {
        int d = dst[i];
        d = (d < 0) ? 0 : ((d >= n) ? n - 1 : d);
        atomicAdd(&cnt[d], 1);
    }
}

__global__ void deg_k(const int* __restrict__ cnt, float* __restrict__ isd,
                      float* __restrict__ sdeg, int n) {
    int i = blockIdx.x * 256 + threadIdx.x;
    if (i < n) {
        float d = (float)cnt[i] + 1.0f;   // +1 self loop
        float r = rsqrtf(d);
        isd[i] = r;
        sdeg[i] = d * r;                  // sqrt(d)
    }
}

__global__ __launch_bounds__(256) void scan1_k(const int* __restrict__ cnt,
                                               int* __restrict__ bsum, int n) {
    __shared__ int red[256];
    int t = threadIdx.x;
    int base = blockIdx.x * 1024 + t * 4;
    int s = 0;
    if (base + 3 < n) {
        int4 v = *(const int4*)&cnt[base];
        s = v.x + v.y + v.z + v.w;
    } else {
#pragma unroll
        for (int k = 0; k < 4; k++) {
            int idx = base + k;
            if (idx < n) s += cnt[idx];
        }
    }
    red[t] = s;
    __syncthreads();
    for (int off = 128; off > 0; off >>= 1) {
        if (t < off) red[t] += red[t + off];
        __syncthreads();
    }
    if (t == 0) bsum[blockIdx.x] = red[0];
}

__global__ __launch_bounds__(256) void scan2_k(const int* __restrict__ bsum,
                                               int* __restrict__ boff, int G,
                                               int* __restrict__ row_end, int E) {
    __shared__ int part[256];
    int t = threadIdx.x;
    int own = (t < G) ? bsum[t] : 0;
    part[t] = own;
    __syncthreads();
    for (int off = 1; off < 256; off <<= 1) {
        int v = (t >= off) ? part[t - off] : 0;
        __syncthreads();
        part[t] += v;
        __syncthreads();
    }
    if (t < G) boff[t] = part[t] - own;   // exclusive
    if (t == 0) row_end[0] = E;           // row_start[n]
}

__global__ __launch_bounds__(256) void scan3_k(const int* __restrict__ cnt,
                                               const int* __restrict__ boff,
                                               int* __restrict__ row_start,
                                               int* __restrict__ cursor, int n) {
    __shared__ int part[256];
    int t = threadIdx.x;
    int base = blockIdx.x * 1024 + t * 4;
    int v[4];
    if (base + 3 < n) {
        int4 q = *(const int4*)&cnt[base];
        v[0] = q.x; v[1] = q.y; v[2] = q.z; v[3] = q.w;
    } else {
#pragma unroll
        for (int k = 0; k < 4; k++) v[k] = (base + k < n) ? cnt[base + k] : 0;
    }
    int s = v[0] + v[1] + v[2] + v[3];
    int own = s;
    part[t] = s;
    __syncthreads();
    for (int off = 1; off < 256; off <<= 1) {
        int q = (t >= off) ? part[t - off] : 0;
        __syncthreads();
        part[t] += q;
        __syncthreads();
    }
    int run = boff[blockIdx.x] + part[t] - own;
#pragma unroll
    for (int k = 0; k < 4; k++) {
        int idx = base + k;
        if (idx < n) {
            row_start[idx] = run;
            cursor[idx] = run;
            run += v[k];
        }
    }
}

__global__ void scatter_edges_k(const int* __restrict__ src, const int* __restrict__ dst,
                                int* __restrict__ cursor, int* __restrict__ esrc, int e, int n) {
    int i = blockIdx.x * 256 + threadIdx.x;
    if (i < e) {
        int d = dst[i];
        d = (d < 0) ? 0 : ((d >= n) ? n - 1 : d);
        int s = src[i];
        s = (s < 0) ? 0 : ((s >= n) ? n - 1 : s);
        int pos = atomicAdd(&cursor[d], 1);
        esrc[pos] = s;
    }
}

// ---------------- bf16 conversion ----------------

__global__ void f2bf_xsc_k(const float* __restrict__ x, const float* __restrict__ isd,
                           unsigned short* __restrict__ xsc, int n4) {
    int i4 = blockIdx.x * 256 + threadIdx.x;
    if (i4 < n4) {
        float si = isd[i4 >> 5];
        float4 v = ((const float4*)x)[i4];
        ushort4 o;
        o.x = f2bf(si * v.x); o.y = f2bf(si * v.y);
        o.z = f2bf(si * v.z); o.w = f2bf(si * v.w);
        ((ushort4*)xsc)[i4] = o;
    }
}

__global__ void wt_all_k(const float* __restrict__ s0, const float* __restrict__ s1,
                         const float* __restrict__ s2, const float* __restrict__ s3,
                         const float* __restrict__ s4, const float* __restrict__ s5,
                         unsigned short* __restrict__ d0, unsigned short* __restrict__ d1,
                         unsigned short* __restrict__ d2, unsigned short* __restrict__ d3,
                         unsigned short* __restrict__ d4, unsigned short* __restrict__ d5) {
    int y = blockIdx.y, k = blockIdx.x, nn = threadIdx.x;
    const float* S;
    unsigned short* D;
    int K;
    switch (y) {
        case 0: S = s0; D = d0; K = 128; break;
        case 1: S = s1; D = d1; K = 128; break;
        case 2: S = s2; D = d2; K = 256; break;
        case 3: S = s3; D = d3; K = 256; break;
        case 4: S = s4; D = d4; K = 256; break;
        default: S = s5; D = d5; K = 256; break;
    }
    if (k >= K) return;
    D[(size_t)nn * K + k] = f2bf(S[(size_t)k * 256 + nn]);
}

// ---------------- bf16 MFMA GEMM: full-width 512-thread blocks, B in VGPRs ------------
// C[M][256] = A[M][K] @ W[K][256]. Block = 512 threads = 8 waves covering a 32-row x
// 256-col tile: wave = (wm in 0..1 row-group of 16) x (wn in 0..3 col-quarter).
// Each wave holds its quarter's B fragments in VGPRs (loaded once; persistent blocks,
// grid-stride over row tiles). The 4 col-quarter waves of a row-group issue IDENTICAL
// A loads -> served by the CU's L1 (16KB tile) => A leaves fabric exactly once.
// mfma(bfrag, afrag, acc): thread owns C-row gr, 4-consecutive-col groups.
// PF: software-pipeline the A tile: prefetch tile rt+gridDim.x into a second register
//     buffer before the MFMA chain of tile rt, hiding global-load latency under
//     MFMA + epilogue. (+CH*4 VGPRs; HEAD variant keeps PF=false for register budget.)
// SPRE: v *= rowscale before bias.  SCALE: v *= rowscale at end.
// STATS: accumulate per-column sum/sumsq of v (f32, pre-bf16-round) -> pstats[block][512]
// HEAD:  no C store; per-row dot with hw (f32), shfl over quad lanes, atomicAdd hout[gr].

template <int K, bool BIAS, bool GELU_, bool SPRE, bool SCALE, bool STATS, bool HEAD, bool PF>
__global__ __launch_bounds__(512) void gemm_bf_k(const unsigned short* __restrict__ A,
                                                 const unsigned short* __restrict__ Wt,
                                                 const float* __restrict__ bias,
                                                 const float* __restrict__ rowscale,
                                                 unsigned short* __restrict__ CB,
                                                 int M,
                                                 const float* __restrict__ hw,
                                                 const float* __restrict__ hb,
                                                 float* __restrict__ hout,
                                                 float* __restrict__ pstats) {
    constexpr int CH = K / 32;
    const int lane = threadIdx.x & 63;
    const int wave = threadIdx.x >> 6;
    const int wm = wave & 1;               // row group (16 rows)
    const int wn = wave >> 1;              // col quarter
    const int l15 = lane & 15;
    const int quad = lane >> 4;

    bf16x8 bfr[CH][4];
#pragma unroll
    for (int c = 0; c < CH; c++)
#pragma unroll
        for (int j = 0; j < 4; j++) {
            int col = wn * 64 + j * 16 + l15;
            bfr[c][j] = *(const bf16x8*)&Wt[(size_t)col * K + c * 32 + quad * 8];
        }

    float hwv[16];
    if (HEAD) {
#pragma unroll
        for (int j = 0; j < 4; j++) {
            float4 w4 = *(const float4*)&hw[wn * 64 + j * 16 + quad * 4];
            hwv[j * 4 + 0] = w4.x; hwv[j * 4 + 1] = w4.y;
            hwv[j * 4 + 2] = w4.z; hwv[j * 4 + 3] = w4.w;
        }
    }
    float sacc[STATS ? 16 : 1], s2acc[STATS ? 16 : 1];
    if (STATS) {
#pragma unroll
        for (int k = 0; k < 16; k++) { sacc[k] = 0.f; s2acc[k] = 0.f; }
    }

    const int nTiles = (M + 31) >> 5;
    const int gstride = gridDim.x;

    bf16x8 a[CH];
    if (PF) {
        int rt = blockIdx.x;
        if (rt < nTiles) {
            int g = rt * 32 + wm * 16 + l15;
            int gc = (g < M) ? g : (M - 1);
            const unsigned short* ap = &A[(size_t)gc * K + quad * 8];
#pragma unroll
            for (int c = 0; c < CH; c++) a[c] = *(const bf16x8*)(ap + c * 32);
        }
    }

    for (int rt = blockIdx.x; rt < nTiles; rt += gstride) {
        int gr = rt * 32 + wm * 16 + l15;

        bf16x8 an[CH];
        if (PF) {
            int rtn = rt + gstride;
            if (rtn < nTiles) {
                int gn = rtn * 32 + wm * 16 + l15;
                int gcn = (gn < M) ? gn : (M - 1);
                const unsigned short* apn = &A[(size_t)gcn * K + quad * 8];
#pragma unroll
                for (int c = 0; c < CH; c++) an[c] = *(const bf16x8*)(apn + c * 32);
            }
        } else {
            int grc = (gr < M) ? gr : (M - 1);
            const unsigned short* ap = &A[(size_t)grc * K + quad * 8];
#pragma unroll
            for (int c = 0; c < CH; c++) a[c] = *(const bf16x8*)(ap + c * 32);
        }

        floatx4 acc[4];
#pragma unroll
        for (int j = 0; j < 4; j++) acc[j] = (floatx4){0.f, 0.f, 0.f, 0.f};
#pragma unroll
        for (int c = 0; c < CH; c++)
#pragma unroll
            for (int j = 0; j < 4; j++)
                acc[j] = __builtin_amdgcn_mfma_f32_16x16x32_bf16(bfr[c][j], a[c], acc[j], 0, 0, 0);

        if (gr < M) {
            float rs = (SPRE || SCALE) ? rowscale[gr] : 1.0f;
            float hpart = 0.f;
#pragma unroll
            for (int j = 0; j < 4; j++) {
                int gc0 = wn * 64 + j * 16 + quad * 4;       // 4 consecutive C-cols
                float4 bv;
                if (BIAS) bv = *(const float4*)&bias[gc0];
                float v0 = acc[j][0], v1 = acc[j][1], v2 = acc[j][2], v3 = acc[j][3];
                if (SPRE) { v0 *= rs; v1 *= rs; v2 *= rs; v3 *= rs; }
                if (BIAS) { v0 += bv.x; v1 += bv.y; v2 += bv.z; v3 += bv.w; }
                if (GELU_) { v0 = gelu_f(v0); v1 = gelu_f(v1); v2 = gelu_f(v2); v3 = gelu_f(v3); }
                if (SCALE) { v0 *= rs; v1 *= rs; v2 *= rs; v3 *= rs; }
                if (STATS) {
                    sacc[j * 4 + 0] += v0; s2acc[j * 4 + 0] += v0 * v0;
                    sacc[j * 4 + 1] += v1; s2acc[j * 4 + 1] += v1 * v1;
                    sacc[j * 4 + 2] += v2; s2acc[j * 4 + 2] += v2 * v2;
                    sacc[j * 4 + 3] += v3; s2acc[j * 4 + 3] += v3 * v3;
                }
                if (HEAD) {
                    hpart += v0 * hwv[j * 4 + 0] + v1 * hwv[j * 4 + 1]
                           + v2 * hwv[j * 4 + 2] + v3 * hwv[j * 4 + 3];
                } else {
                    ushort4 o;
                    o.x = f2bf(v0); o.y = f2bf(v1); o.z = f2bf(v2); o.w = f2bf(v3);
                    *(ushort4*)&CB[(size_t)gr * DH + gc0] = o;
                }
            }
            if (HEAD) {
                // lanes sharing a row are {l15 + 16q}: same l15 => same gr (no
                // divergence across partners since M rows never split a 16-group)
                hpart += __shfl_xor(hpart, 16, 64);
                hpart += __shfl_xor(hpart, 32, 64);
                if (quad == 0)
                    atomicAdd(&hout[gr], hpart + (wn == 0 ? hb[0] : 0.f));
            }
        }

        if (PF) {
#pragma unroll
            for (int c = 0; c < CH; c++) a[c] = an[c];
        }
    }

    if (STATS) {
        // butterfly over the 16 lanes (l15) that share this thread's 16 columns
#pragma unroll
        for (int m = 1; m < 16; m <<= 1) {
#pragma unroll
            for (int k = 0; k < 16; k++) {
                sacc[k] += __shfl_xor(sacc[k], m, 64);
                s2acc[k] += __shfl_xor(s2acc[k], m, 64);
            }
        }
        __shared__ float st[STATS ? 1024 : 1];
        if (l15 == 0) {
#pragma unroll
            for (int j = 0; j < 4; j++)
#pragma unroll
                for (int k = 0; k < 4; k++) {
                    int col = wn * 64 + j * 16 + quad * 4 + k;
                    st[wm * 512 + col] = sacc[j * 4 + k];
                    st[wm * 512 + 256 + col] = s2acc[j * 4 + k];
                }
        }
        __syncthreads();
        int t = threadIdx.x;
        pstats[(size_t)blockIdx.x * 512 + t] = st[t] + st[512 + t];
    }
}

// ---------------- layer-0 aggregation on xsc (8-deep batch: 48 VGPR / ~47% occ) ------

__global__ __launch_bounds__(256) void agg_x_k(const unsigned short* __restrict__ xsc,
                                               const int* __restrict__ esrc,
                                               const int* __restrict__ row_start,
                                               const float* __restrict__ isd,
                                               unsigned short* __restrict__ out, int n) {
    int half = threadIdx.x >> 5;
    int sub = threadIdx.x & 31;
    int i = blockIdx.x * 8 + half;
    if (i >= n) return;
    int beg = row_start[i], end = row_start[i + 1];
    int c = sub * 4;
    float acc[4] = {0.f, 0.f, 0.f, 0.f};
    addbf4(acc, *(const ushort4*)&xsc[(size_t)i * 128 + c]);   // self
    int e = beg;
    for (; e + 7 < end; e += 8) {
        int s[8];
        ushort4 u[8];
#pragma unroll
        for (int k = 0; k < 8; k++) s[k] = esrc[e + k];
#pragma unroll
        for (int k = 0; k < 8; k++) u[k] = *(const ushort4*)&xsc[(size_t)s[k] * 128 + c];
#pragma unroll
        for (int k = 0; k < 8; k++) addbf4(acc, u[k]);
    }
    for (; e + 1 < end; e += 2) {
        int s0 = esrc[e], s1 = esrc[e + 1];
        ushort4 a = *(const ushort4*)&xsc[(size_t)s0 * 128 + c];
        ushort4 b = *(const ushort4*)&xsc[(size_t)s1 * 128 + c];
        addbf4(acc, a);
        addbf4(acc, b);
    }
    if (e < end)
        addbf4(acc, *(const ushort4*)&xsc[(size_t)esrc[e] * 128 + c]);
    float si = isd[i];
    ushort4 o;
    o.x = f2bf(si * acc[0]); o.y = f2bf(si * acc[1]);
    o.z = f2bf(si * acc[2]); o.w = f2bf(si * acc[3]);
    *(ushort4*)&out[(size_t)i * 128 + c] = o;
}

// ---------------- layers 1,2 aggregation + BN partials (8-deep batch) ----------------

__global__ __launch_bounds__(256) void agg_h_k(const unsigned short* __restrict__ hws,
                                               const int* __restrict__ esrc,
                                               const int* __restrict__ row_start,
                                               const float* __restrict__ isd,
                                               const float* __restrict__ bias,
                                               unsigned short* __restrict__ out,
                                               float* __restrict__ pbuf, int n) {
    __shared__ float ls[2048];
    int t = threadIdx.x;
    int half = t >> 5;
    int sub = t & 31;
    int c = sub * 8;
    int i = blockIdx.x * 8 + half;

    float o[8] = {0.f, 0.f, 0.f, 0.f, 0.f, 0.f, 0.f, 0.f};
    if (i < n) {
        int beg = row_start[i], end = row_start[i + 1];
        float acc[8] = {0.f, 0.f, 0.f, 0.f, 0.f, 0.f, 0.f, 0.f};
        addbf8(acc, *(const uint4*)&hws[(size_t)i * DH + c]);   // self
        int e = beg;
        for (; e + 7 < end; e += 8) {
            int s[8];
            uint4 u[8];
#pragma unroll
            for (int k = 0; k < 8; k++) s[k] = esrc[e + k];
#pragma unroll
            for (int k = 0; k < 8; k++) u[k] = *(const uint4*)&hws[(size_t)s[k] * DH + c];
#pragma unroll
            for (int k = 0; k < 8; k++) addbf8(acc, u[k]);
        }
        for (; e + 1 < end; e += 2) {
            int s0 = esrc[e], s1 = esrc[e + 1];
            uint4 a = *(const uint4*)&hws[(size_t)s0 * DH + c];
            uint4 b = *(const uint4*)&hws[(size_t)s1 * DH + c];
            addbf8(acc, a);
            addbf8(acc, b);
        }
        if (e < end)
            addbf8(acc, *(const uint4*)&hws[(size_t)esrc[e] * DH + c]);
        float si = isd[i];
        float4 b0 = *(const float4*)&bias[c];
        float4 b1 = *(const float4*)&bias[c + 4];
        o[0] = si * acc[0] + b0.x; o[1] = si * acc[1] + b0.y;
        o[2] = si * acc[2] + b0.z; o[3] = si * acc[3] + b0.w;
        o[4] = si * acc[4] + b1.x; o[5] = si * acc[5] + b1.y;
        o[6] = si * acc[6] + b1.z; o[7] = si * acc[7] + b1.w;
        unsigned short ob[8];
#pragma unroll
        for (int k = 0; k < 8; k++) ob[k] = f2bf(o[k]);
        *(uint4*)&out[(size_t)i * DH + c] = *(const uint4*)ob;
    }
    *(float4*)&ls[half * 256 + c]     = make_float4(o[0], o[1], o[2], o[3]);
    *(float4*)&ls[half * 256 + c + 4] = make_float4(o[4], o[5], o[6], o[7]);
    __syncthreads();
    float s = 0.f, s2 = 0.f;
#pragma unroll
    for (int h = 0; h < 8; h++) {
        float v = ls[h * 256 + t];
        s += v;
        s2 += v * v;
    }
    pbuf[(size_t)blockIdx.x * 512 + t] = s;
    pbuf[(size_t)blockIdx.x * 512 + 256 + t] = s2;
}

// reduce pbuf[nb][512] -> pbuf2[64][512]
__global__ __launch_bounds__(256) void bn_reduce_k(const float* __restrict__ pbuf,
                                                   float* __restrict__ pbuf2, int nb) {
    int t = threadIdx.x;
    float s = 0.f, s2 = 0.f;
    for (int r = blockIdx.x; r < nb; r += gridDim.x) {
        s += pbuf[(size_t)r * 512 + t];
        s2 += pbuf[(size_t)r * 512 + 256 + t];
    }
    pbuf2[(size_t)blockIdx.x * 512 + t] = s;
    pbuf2[(size_t)blockIdx.x * 512 + 256 + t] = s2;
}

__global__ void bn_finalize_k(const float* __restrict__ pbuf2, int nrows,
                              const float* __restrict__ g, const float* __restrict__ b,
                              float* __restrict__ ss, float inv_n) {
    int j = threadIdx.x;
    float s = 0.f, s2 = 0.f;
    for (int r = 0; r < nrows; r++) {
        s += pbuf2[(size_t)r * 512 + j];
        s2 += pbuf2[(size_t)r * 512 + 256 + j];
    }
    float mu = s * inv_n;
    float var = s2 * inv_n - mu * mu;
    float sc = g[j] * rsqrtf(var + EPSV);
    ss[j] = sc;
    ss[DH + j] = b[j] - mu * sc;
}

__global__ __launch_bounds__(256) void bn_act_res_k(const unsigned short* __restrict__ gcn_bf,
                                                    const float* __restrict__ ss,
                                                    const unsigned short* __restrict__ resid_bf,
                                                    unsigned short* __restrict__ out_bf, int n) {
    size_t idx = ((size_t)blockIdx.x * 256 + threadIdx.x) * 8;
    if (idx >= (size_t)n * DH) return;
    int j = (int)(idx & (DH - 1));
    uint4 gv = *(const uint4*)&gcn_bf[idx];
    uint4 rv = *(const uint4*)&resid_bf[idx];
    const unsigned short* gp = (const unsigned short*)&gv;
    const unsigned short* rp = (const unsigned short*)&rv;
    float4 sc0 = *(const float4*)&ss[j];
    float4 sc1 = *(const float4*)&ss[j + 4];
    float4 sh0 = *(const float4*)&ss[DH + j];
    float4 sh1 = *(const float4*)&ss[DH + j + 4];
    float scv[8] = {sc0.x, sc0.y, sc0.z, sc0.w, sc1.x, sc1.y, sc1.z, sc1.w};
    float shv[8] = {sh0.x, sh0.y, sh0.z, sh0.w, sh1.x, sh1.y, sh1.z, sh1.w};
    unsigned short ob[8];
#pragma unroll
    for (int k = 0; k < 8; k++) {
        float v = bf2f(gp[k]) * scv[k] + shv[k];
        ob[k] = f2bf(gelu_f(v) + bf2f(rp[k]));
    }
    *(uint4*)&out_bf[idx] = *(const uint4*)ob;
}

// ---------------- launch ----------------

extern "C" void kernel_launch(void* const* d_in, const int* in_sizes, int n_in,
                              void* d_out, int out_size, void* d_ws, size_t ws_size,
                              hipStream_t stream) {
    const float* x = (const float*)d_in[0];
    const int* eidx = (const int*)d_in[1];       // int64 in ref -> int32 on device
    const float* conv_w0 = (const float*)d_in[3];
    const float* conv_b0 = (const float*)d_in[4];
    const float* conv_w1 = (const float*)d_in[5];
    const float* conv_b1 = (const float*)d_in[6];
    const float* conv_w2 = (const float*)d_in[7];
    const float* conv_b2 = (const float*)d_in[8];
    const float* bn_g0 = (const float*)d_in[9];
    const float* bn_b0 = (const float*)d_in[10];
    const float* bn_g1 = (const float*)d_in[11];
    const float* bn_b1 = (const float*)d_in[12];
    const float* bn_g2 = (const float*)d_in[13];
    const float* bn_b2 = (const float*)d_in[14];
    const float* proj_w = (const float*)d_in[15];
    const float* proj_b = (const float*)d_in[16];
    const float* lin_w0 = (const float*)d_in[17];
    const float* lin_b0 = (const float*)d_in[18];
    const float* lin_w1 = (const float*)d_in[19];
    const float* lin_b1 = (const float*)d_in[20];
    const float* head_w = (const float*)d_in[21];
    const float* head_b = (const float*)d_in[22];

    const int N = in_sizes[2];
    const int E = in_sizes[1] / 2;
    const int* esrc_in = eidx;
    const int* edst_in = eidx + E;

    char* ws = (char*)d_ws;
    auto alloc = [&](size_t b) -> char* {
        char* p = ws;
        ws += (b + 255) & ~(size_t)255;
        return p;
    };
    unsigned short* h1_bf = (unsigned short*)alloc((size_t)N * DH * 2);
    unsigned short* h2_bf = (unsigned short*)alloc((size_t)N * DH * 2);
    unsigned short* hw_bf = (unsigned short*)alloc((size_t)N * DH * 2);
    unsigned short* pj_bf = (unsigned short*)alloc((size_t)N * DH * 2);
    unsigned short* gcn_bf = (unsigned short*)alloc((size_t)N * DH * 2);
    unsigned short* xsc = (unsigned short*)alloc((size_t)N * 128 * 2);
    unsigned short* axs = (unsigned short*)alloc((size_t)N * 128 * 2);   // S·x ; later pbuf
    float* pbuf2 = (float*)alloc((size_t)256 * 512 * 4);
    unsigned short* w0t = (unsigned short*)alloc((size_t)256 * 128 * 2);
    unsigned short* pjt = (unsigned short*)alloc((size_t)256 * 128 * 2);
    unsigned short* w1t = (unsigned short*)alloc((size_t)256 * 256 * 2);
    unsigned short* w2t = (unsigned short*)alloc((size_t)256 * 256 * 2);
    unsigned short* l0t = (unsigned short*)alloc((size_t)256 * 256 * 2);
    unsigned short* l1t = (unsigned short*)alloc((size_t)256 * 256 * 2);
    int* cnt = (int*)alloc((size_t)N * 4);
    int* row_start = (int*)alloc((size_t)(N + 1) * 4);
    int* cursor = (int*)alloc((size_t)N * 4);
    int* esrc = (int*)alloc((size_t)E * 4);
    float* isd = (float*)alloc((size_t)N * 4);
    float* sdeg = (float*)alloc((size_t)N * 4);
    float* ss = (float*)alloc(2 * DH * 4);
    int* bsum = (int*)alloc(256 * 4);
    int* boff = (int*)alloc(256 * 4);

    // pbuf (agg_h BN partials, gHalf*512 floats = 12.8MB) aliases axs (dead after conv0)
    float* pbuf = (float*)axs;

    const int gE = (E + 255) / 256;
    const int gN = (N + 255) / 256;
    const int gHalf = (N + 7) / 8;
    const int gElem = (int)(((size_t)N * DH / 8 + 255) / 256);
    const int gScan = (N + 1023) / 1024;
    const int gGemm = 256;                       // persistent full-width blocks (1/CU)
    const float inv_n = 1.0f / (float)N;

    // CSR build
    hipMemsetAsync(cnt, 0, (size_t)N * 4, stream);
    hipMemsetAsync(d_out, 0, (size_t)N * 4, stream);   // head accumulates via atomicAdd
    count_edges_k<<<gE, 256, 0, stream>>>(edst_in, cnt, E, N);
    deg_k<<<gN, 256, 0, stream>>>(cnt, isd, sdeg, N);
    scan1_k<<<gScan, 256, 0, stream>>>(cnt, bsum, N);
    scan2_k<<<1, 256, 0, stream>>>(bsum, boff, gScan, &row_start[N], E);
    scan3_k<<<gScan, 256, 0, stream>>>(cnt, boff, row_start, cursor, N);
    scatter_edges_k<<<gE, 256, 0, stream>>>(esrc_in, edst_in, cursor, esrc, E, N);

    // weights + xsc = isd*x (bf16)
    wt_all_k<<<dim3(256, 6), 256, 0, stream>>>(conv_w0, proj_w, conv_w1, conv_w2, lin_w0, lin_w1,
                                               w0t, pjt, w1t, w2t, l0t, l1t);
    f2bf_xsc_k<<<(N * 128 / 4 + 255) / 256, 256, 0, stream>>>(x, isd, xsc, N * 128 / 4);

    // ---- layer 0 ----
    agg_x_k<<<gHalf, 256, 0, stream>>>(xsc, esrc, row_start, isd, axs, N);
    // proj: (xsc @ pjt) * sdeg + proj_b   (= x @ proj_w + proj_b, since xsc = isd*x)
    gemm_bf_k<128, true, false, true, false, false, false, true><<<gGemm, 512, 0, stream>>>(
        xsc, pjt, proj_b, sdeg, pj_bf, N, nullptr, nullptr, nullptr, nullptr);
    // conv0 GEMM with fused BN stats (f32, pre-round) -> pbuf2[0..gGemm)
    gemm_bf_k<128, true, false, false, false, true, false, true><<<gGemm, 512, 0, stream>>>(
        axs, w0t, conv_b0, nullptr, gcn_bf, N, nullptr, nullptr, nullptr, pbuf2);
    bn_finalize_k<<<1, DH, 0, stream>>>(pbuf2, gGemm, bn_g0, bn_b0, ss, inv_n);
    bn_act_res_k<<<gElem, 256, 0, stream>>>(gcn_bf, ss, pj_bf, h1_bf, N);

    // ---- layer 1 ----
    gemm_bf_k<256, false, false, false, true, false, false, true><<<gGemm, 512, 0, stream>>>(
        h1_bf, w1t, nullptr, isd, hw_bf, N, nullptr, nullptr, nullptr, nullptr);
    agg_h_k<<<gHalf, 256, 0, stream>>>(hw_bf, esrc, row_start, isd, conv_b1, gcn_bf, pbuf, N);
    bn_reduce_k<<<64, 256, 0, stream>>>(pbuf, pbuf2, gHalf);
    bn_finalize_k<<<1, DH, 0, stream>>>(pbuf2, 64, bn_g1, bn_b1, ss, inv_n);
    bn_act_res_k<<<gElem, 256, 0, stream>>>(gcn_bf, ss, h1_bf, h2_bf, N);

    // ---- layer 2 ----
    gemm_bf_k<256, false, false, false, true, false, false, true><<<gGemm, 512, 0, stream>>>(
        h2_bf, w2t, nullptr, isd, hw_bf, N, nullptr, nullptr, nullptr, nullptr);
    agg_h_k<<<gHalf, 256, 0, stream>>>(hw_bf, esrc, row_start, isd, conv_b2, gcn_bf, pbuf, N);
    bn_reduce_k<<<64, 256, 0, stream>>>(pbuf, pbuf2, gHalf);
    bn_finalize_k<<<1, DH, 0, stream>>>(pbuf2, 64, bn_g2, bn_b2, ss, inv_n);
    bn_act_res_k<<<gElem, 256, 0, stream>>>(gcn_bf, ss, h2_bf, h1_bf, N);   // h3

    // ---- MLP + head ----
    gemm_bf_k<256, true, true, false, false, false, false, true><<<gGemm, 512, 0, stream>>>(
        h1_bf, l0t, lin_b0, nullptr, h2_bf, N, nullptr, nullptr, nullptr, nullptr);
    // final GEMM with fused head: no C materialization, atomic row-dot into d_out
    gemm_bf_k<256, true, true, false, false, false, true, false><<<gGemm, 512, 0, stream>>>(
        h2_bf, l1t, lin_b1, nullptr, nullptr, N, head_w, head_b, (float*)d_out, nullptr);
}

// Round 3
// 617.013 us; speedup vs baseline: 1.2597x; 1.1590x over previous
//
#include <hip/hip_runtime.h>
#include <math.h>

constexpr int DH = 256;
#define EPSV 1e-5f

typedef __bf16 bf16_t;
typedef bf16_t bf16x8 __attribute__((ext_vector_type(8)));
typedef float floatx4 __attribute__((ext_vector_type(4)));

// fast gelu: tanh via hardware exp (v_exp_f32)
__device__ __forceinline__ float gelu_f(float x) {
    float x3 = x * x * x;
    float z = 0.7978845608028654f * (x + 0.044715f * x3);
    float e = __expf(2.0f * z);
    float t = 1.0f - 2.0f / (e + 1.0f);
    return 0.5f * x * (1.0f + t);
}

__device__ __forceinline__ unsigned short f2bf(float x) {
    unsigned int u = __float_as_uint(x);
    u += 0x7FFFu + ((u >> 16) & 1u);
    return (unsigned short)(u >> 16);
}

__device__ __forceinline__ float bf2f(unsigned short u) {
    return __uint_as_float(((unsigned int)u) << 16);
}

__device__ __forceinline__ void addbf8(float* acc, uint4 u) {
    const unsigned short* p = (const unsigned short*)&u;
#pragma unroll
    for (int k = 0; k < 8; k++) acc[k] += bf2f(p[k]);
}

__device__ __forceinline__ void addbf4(float* acc, ushort4 u) {
    acc[0] += bf2f(u.x);
    acc[1] += bf2f(u.y);
    acc[2] += bf2f(u.z);
    acc[3] += bf2f(u.w);
}

// ---------------- CSR build ----------------

__global__ void count_edges_k(const int* __restrict__ dst, int* __restrict__ cnt, int e, int n) {
    int i = blockIdx.x * 256 + threadIdx.x;
    if (i < e) {
        int d = dst[i];
        d = (d < 0) ? 0 : ((d >= n) ? n - 1 : d);
        atomicAdd(&cnt[d], 1);
    }
}

// fused scan1+scan2+scan3+deg: 49 blocks, all co-resident (<< 256 CUs); global sync via
// write -> threadfence -> atomic flag -> spin (each block increments BEFORE spinning, so
// the flag reaches G without requiring spinners to exit).
__global__ __launch_bounds__(256) void scan_all_k(const int* __restrict__ cnt,
                                                  int* __restrict__ bsum,
                                                  int* __restrict__ flag,
                                                  int* __restrict__ row_start,
                                                  int* __restrict__ cursor,
                                                  float* __restrict__ isd,
                                                  float* __restrict__ sdeg,
                                                  int n, int G, int E) {
    __shared__ int part[256];
    __shared__ int bs[256];
    __shared__ int boffsh;
    int t = threadIdx.x, b = blockIdx.x;
    int base = b * 1024 + t * 4;
    int v[4];
    if (base + 3 < n) {
        int4 q = *(const int4*)&cnt[base];
        v[0] = q.x; v[1] = q.y; v[2] = q.z; v[3] = q.w;
    } else {
#pragma unroll
        for (int k = 0; k < 4; k++) v[k] = (base + k < n) ? cnt[base + k] : 0;
    }
    int s = v[0] + v[1] + v[2] + v[3];
    part[t] = s;
    __syncthreads();
    for (int off = 1; off < 256; off <<= 1) {
        int q = (t >= off) ? part[t - off] : 0;
        __syncthreads();
        part[t] += q;
        __syncthreads();
    }
    if (t == 0) {
        bsum[b] = part[255];
        __threadfence();
        atomicAdd(flag, 1);
        while (__hip_atomic_load(flag, __ATOMIC_ACQUIRE, __HIP_MEMORY_SCOPE_AGENT) < G) {}
    }
    __syncthreads();
    if (t < G) bs[t] = bsum[t];
    __syncthreads();
    if (t == 0) {
        int a = 0;
        for (int k = 0; k < b; k++) a += bs[k];
        boffsh = a;
    }
    __syncthreads();
    int run = boffsh + part[t] - s;   // exclusive prefix for this thread's 4 entries
#pragma unroll
    for (int k = 0; k < 4; k++) {
        int idx = base + k;
        if (idx < n) {
            row_start[idx] = run;
            cursor[idx] = run;
            float d = (float)v[k] + 1.0f;   // +1 self loop
            float r = rsqrtf(d);
            isd[idx] = r;
            sdeg[idx] = d * r;
            run += v[k];
        }
    }
    if (b == 0 && t == 0) row_start[n] = E;
}

__global__ void scatter_edges_k(const int* __restrict__ src, const int* __restrict__ dst,
                                int* __restrict__ cursor, int* __restrict__ esrc, int e, int n) {
    int i = blockIdx.x * 256 + threadIdx.x;
    if (i < e) {
        int d = dst[i];
        d = (d < 0) ? 0 : ((d >= n) ? n - 1 : d);
        int s = src[i];
        s = (s < 0) ? 0 : ((s >= n) ? n - 1 : s);
        int pos = atomicAdd(&cursor[d], 1);
        esrc[pos] = s;
    }
}

// ---------------- weights transpose + xsc conversion, one launch ----------------
// blocks [0,1536): weight transposes (6 planes x 256); blocks [1536, ...): xsc = isd*x.

__global__ void prep_k(const float* __restrict__ s0, const float* __restrict__ s1,
                       const float* __restrict__ s2, const float* __restrict__ s3,
                       const float* __restrict__ s4, const float* __restrict__ s5,
                       unsigned short* __restrict__ d0, unsigned short* __restrict__ d1,
                       unsigned short* __restrict__ d2, unsigned short* __restrict__ d3,
                       unsigned short* __restrict__ d4, unsigned short* __restrict__ d5,
                       const float* __restrict__ x, const float* __restrict__ isd,
                       unsigned short* __restrict__ xsc, int n4) {
    int b = blockIdx.x;
    if (b < 1536) {
        int y = b >> 8, k = b & 255, nn = threadIdx.x;
        const float* S;
        unsigned short* D;
        int K;
        switch (y) {
            case 0: S = s0; D = d0; K = 128; break;
            case 1: S = s1; D = d1; K = 128; break;
            case 2: S = s2; D = d2; K = 256; break;
            case 3: S = s3; D = d3; K = 256; break;
            case 4: S = s4; D = d4; K = 256; break;
            default: S = s5; D = d5; K = 256; break;
        }
        if (k >= K) return;
        D[(size_t)nn * K + k] = f2bf(S[(size_t)k * 256 + nn]);
    } else {
        int i4 = (b - 1536) * 256 + threadIdx.x;
        if (i4 < n4) {
            float si = isd[i4 >> 5];
            float4 v = ((const float4*)x)[i4];
            ushort4 o;
            o.x = f2bf(si * v.x); o.y = f2bf(si * v.y);
            o.z = f2bf(si * v.z); o.w = f2bf(si * v.w);
            ((ushort4*)xsc)[i4] = o;
        }
    }
}

// ---------------- bf16 MFMA GEMM: full-width 512-thread blocks, B in VGPRs ------------
// C[M][256] = A[M][K] @ W[K][256]. Block = 512 threads = 8 waves covering a 32-row x
// 256-col tile: wave = (wm: row-group of 16) x (wn: col-quarter). B fragments persist in
// VGPRs; persistent blocks grid-stride over row tiles.
// PF:    register prefetch of next A tile (plain-A path).
// FUSEA: A is produced on the fly: t = gelu(gcnA*sc+sh) + resid (BN+act+residual fused),
//        staged through XOR-swizzled double-buffered LDS (one barrier/tile); raw loads
//        for the next tile are prefetched before the barrier. WRITEH: also store t -> hwr.
// SPRE/SCALE: rowscale pre-bias / at end.  STATS: per-column sum/sumsq -> pstats.
// HEAD:  no C store; row-dot with hw; combine the 4 col-quarter waves via LDS, one
//        non-atomic store per row (no d_out memset needed).

template <int K, bool BIAS, bool GELU_, bool SPRE, bool SCALE, bool STATS, bool HEAD,
          bool PF, bool FUSEA, bool WRITEH>
__global__ __launch_bounds__(512) void gemm_bf_k(const unsigned short* __restrict__ A,
                                                 const unsigned short* __restrict__ Wt,
                                                 const float* __restrict__ bias,
                                                 const float* __restrict__ rowscale,
                                                 unsigned short* __restrict__ CB,
                                                 int M,
                                                 const float* __restrict__ hw,
                                                 const float* __restrict__ hb,
                                                 float* __restrict__ hout,
                                                 float* __restrict__ pstats,
                                                 const unsigned short* __restrict__ resid,
                                                 const float* __restrict__ ssp,
                                                 unsigned short* __restrict__ hwr) {
    constexpr int CH = K / 32;
    const int lane = threadIdx.x & 63;
    const int wave = threadIdx.x >> 6;
    const int wm = wave & 1;               // row group (16 rows)
    const int wn = wave >> 1;              // col quarter
    const int l15 = lane & 15;
    const int quad = lane >> 4;

    __shared__ unsigned short al[FUSEA ? 2 * 32 * 256 : 1];
    __shared__ float hsum4[HEAD ? 128 : 1];
    __shared__ float st[STATS ? 1024 : 1];

    bf16x8 bfr[CH][4];
#pragma unroll
    for (int c = 0; c < CH; c++)
#pragma unroll
        for (int j = 0; j < 4; j++) {
            int col = wn * 64 + j * 16 + l15;
            bfr[c][j] = *(const bf16x8*)&Wt[(size_t)col * K + c * 32 + quad * 8];
        }

    float hwv[16];
    if (HEAD) {
#pragma unroll
        for (int j = 0; j < 4; j++) {
            float4 w4 = *(const float4*)&hw[wn * 64 + j * 16 + quad * 4];
            hwv[j * 4 + 0] = w4.x; hwv[j * 4 + 1] = w4.y;
            hwv[j * 4 + 2] = w4.z; hwv[j * 4 + 3] = w4.w;
        }
    }
    float sacc[STATS ? 16 : 1], s2acc[STATS ? 16 : 1];
    if (STATS) {
#pragma unroll
        for (int k = 0; k < 16; k++) { sacc[k] = 0.f; s2acc[k] = 0.f; }
    }

    const int nTiles = (M + 31) >> 5;
    const int gstride = gridDim.x;

    // FUSEA thread mapping for the transform stage
    const int tr = threadIdx.x >> 4;            // local row 0..31
    const int tc = (threadIdx.x & 15) * 16;     // col base (16 cols/thread)
    const int sw = (tr & 7) << 3;               // LDS slot swizzle (ushort units)
    const int rr = wm * 16 + l15;               // fragment row
    const int rsw = (rr & 7) << 3;

    bf16x8 a[CH];
    uint4 g0, g1, r0, r1;
    if (FUSEA) {
        int rt0 = blockIdx.x;
        if (rt0 < nTiles) {
            int grow = rt0 * 32 + tr;
            int gc = (grow < M) ? grow : (M - 1);
            const unsigned short* gp = &A[(size_t)gc * 256 + tc];
            const unsigned short* rp = &resid[(size_t)gc * 256 + tc];
            g0 = *(const uint4*)gp; g1 = *(const uint4*)(gp + 8);
            r0 = *(const uint4*)rp; r1 = *(const uint4*)(rp + 8);
        }
    } else if (PF) {
        int rt0 = blockIdx.x;
        if (rt0 < nTiles) {
            int g = rt0 * 32 + wm * 16 + l15;
            int gc = (g < M) ? g : (M - 1);
            const unsigned short* ap = &A[(size_t)gc * K + quad * 8];
#pragma unroll
            for (int c = 0; c < CH; c++) a[c] = *(const bf16x8*)(ap + c * 32);
        }
    }

    int p = 0;
    for (int rt = blockIdx.x; rt < nTiles; rt += gstride) {
        int gr = rt * 32 + wm * 16 + l15;

        if constexpr (FUSEA) {
            // transform current raw tile -> bf16, LDS (+ optional h store)
            int grow = rt * 32 + tr;
            float4 sa = *(const float4*)&ssp[tc];
            float4 sb = *(const float4*)&ssp[tc + 4];
            float4 sc = *(const float4*)&ssp[tc + 8];
            float4 sd = *(const float4*)&ssp[tc + 12];
            float4 ha = *(const float4*)&ssp[256 + tc];
            float4 hbv = *(const float4*)&ssp[256 + tc + 4];
            float4 hc = *(const float4*)&ssp[256 + tc + 8];
            float4 hd = *(const float4*)&ssp[256 + tc + 12];
            float scv[16] = {sa.x, sa.y, sa.z, sa.w, sb.x, sb.y, sb.z, sb.w,
                             sc.x, sc.y, sc.z, sc.w, sd.x, sd.y, sd.z, sd.w};
            float shv[16] = {ha.x, ha.y, ha.z, ha.w, hbv.x, hbv.y, hbv.z, hbv.w,
                             hc.x, hc.y, hc.z, hc.w, hd.x, hd.y, hd.z, hd.w};
            const unsigned short* gg = (const unsigned short*)&g0;   // g0,g1 contiguous? no:
            unsigned short gbuf[16], rbuf[16];
            *(uint4*)&gbuf[0] = g0; *(uint4*)&gbuf[8] = g1;
            *(uint4*)&rbuf[0] = r0; *(uint4*)&rbuf[8] = r1;
            (void)gg;
            unsigned short hv[16];
#pragma unroll
            for (int k = 0; k < 16; k++) {
                float v = bf2f(gbuf[k]) * scv[k] + shv[k];
                hv[k] = f2bf(gelu_f(v) + bf2f(rbuf[k]));
            }
            *(uint4*)&al[p * 8192 + tr * 256 + (tc ^ sw)] = *(const uint4*)&hv[0];
            *(uint4*)&al[p * 8192 + tr * 256 + ((tc + 8) ^ sw)] = *(const uint4*)&hv[8];
            if (WRITEH && grow < M) {
                *(uint4*)&hwr[(size_t)grow * 256 + tc] = *(const uint4*)&hv[0];
                *(uint4*)&hwr[(size_t)grow * 256 + tc + 8] = *(const uint4*)&hv[8];
            }
            // prefetch next raw tile (lands during MFMA of this tile)
            int rtn = rt + gstride;
            if (rtn < nTiles) {
                int gn = rtn * 32 + tr;
                int gc2 = (gn < M) ? gn : (M - 1);
                const unsigned short* gp = &A[(size_t)gc2 * 256 + tc];
                const unsigned short* rp = &resid[(size_t)gc2 * 256 + tc];
                g0 = *(const uint4*)gp; g1 = *(const uint4*)(gp + 8);
                r0 = *(const uint4*)rp; r1 = *(const uint4*)(rp + 8);
            }
            __syncthreads();
#pragma unroll
            for (int c = 0; c < CH; c++)
                a[c] = *(const bf16x8*)&al[p * 8192 + rr * 256 + ((c * 32 + quad * 8) ^ rsw)];
        } else if constexpr (!PF) {
            int grc = (gr < M) ? gr : (M - 1);
            const unsigned short* ap = &A[(size_t)grc * K + quad * 8];
#pragma unroll
            for (int c = 0; c < CH; c++) a[c] = *(const bf16x8*)(ap + c * 32);
        }

        bf16x8 an[CH];
        if (PF && !FUSEA) {
            int rtn = rt + gstride;
            if (rtn < nTiles) {
                int gn = rtn * 32 + wm * 16 + l15;
                int gcn = (gn < M) ? gn : (M - 1);
                const unsigned short* apn = &A[(size_t)gcn * K + quad * 8];
#pragma unroll
                for (int c = 0; c < CH; c++) an[c] = *(const bf16x8*)(apn + c * 32);
            }
        }

        floatx4 acc[4];
#pragma unroll
        for (int j = 0; j < 4; j++) acc[j] = (floatx4){0.f, 0.f, 0.f, 0.f};
#pragma unroll
        for (int c = 0; c < CH; c++)
#pragma unroll
            for (int j = 0; j < 4; j++)
                acc[j] = __builtin_amdgcn_mfma_f32_16x16x32_bf16(bfr[c][j], a[c], acc[j], 0, 0, 0);

        float hpart = 0.f;
        if (gr < M) {
            float rs = (SPRE || SCALE) ? rowscale[gr] : 1.0f;
#pragma unroll
            for (int j = 0; j < 4; j++) {
                int gc0 = wn * 64 + j * 16 + quad * 4;       // 4 consecutive C-cols
                float4 bv;
                if (BIAS) bv = *(const float4*)&bias[gc0];
                float v0 = acc[j][0], v1 = acc[j][1], v2 = acc[j][2], v3 = acc[j][3];
                if (SPRE) { v0 *= rs; v1 *= rs; v2 *= rs; v3 *= rs; }
                if (BIAS) { v0 += bv.x; v1 += bv.y; v2 += bv.z; v3 += bv.w; }
                if (GELU_) { v0 = gelu_f(v0); v1 = gelu_f(v1); v2 = gelu_f(v2); v3 = gelu_f(v3); }
                if (SCALE) { v0 *= rs; v1 *= rs; v2 *= rs; v3 *= rs; }
                if (STATS) {
                    sacc[j * 4 + 0] += v0; s2acc[j * 4 + 0] += v0 * v0;
                    sacc[j * 4 + 1] += v1; s2acc[j * 4 + 1] += v1 * v1;
                    sacc[j * 4 + 2] += v2; s2acc[j * 4 + 2] += v2 * v2;
                    sacc[j * 4 + 3] += v3; s2acc[j * 4 + 3] += v3 * v3;
                }
                if (HEAD) {
                    hpart += v0 * hwv[j * 4 + 0] + v1 * hwv[j * 4 + 1]
                           + v2 * hwv[j * 4 + 2] + v3 * hwv[j * 4 + 3];
                } else {
                    ushort4 o;
                    o.x = f2bf(v0); o.y = f2bf(v1); o.z = f2bf(v2); o.w = f2bf(v3);
                    *(ushort4*)&CB[(size_t)gr * DH + gc0] = o;
                }
            }
        }
        if constexpr (HEAD) {
            // sum over the 4 quad lanes sharing this row, then combine the 4 wn waves
            hpart += __shfl_xor(hpart, 16, 64);
            hpart += __shfl_xor(hpart, 32, 64);
            if (quad == 0) hsum4[wn * 32 + wm * 16 + l15] = hpart;
            __syncthreads();
            if (threadIdx.x < 32) {
                int grow = rt * 32 + (int)threadIdx.x;
                if (grow < M)
                    hout[grow] = hsum4[threadIdx.x] + hsum4[32 + threadIdx.x] +
                                 hsum4[64 + threadIdx.x] + hsum4[96 + threadIdx.x] + hb[0];
            }
            __syncthreads();
        }

        if constexpr (FUSEA) {
            p ^= 1;
        } else if (PF) {
#pragma unroll
            for (int c = 0; c < CH; c++) a[c] = an[c];
        }
    }

    if (STATS) {
        // butterfly over the 16 lanes (l15) that share this thread's 16 columns
#pragma unroll
        for (int m = 1; m < 16; m <<= 1) {
#pragma unroll
            for (int k = 0; k < 16; k++) {
                sacc[k] += __shfl_xor(sacc[k], m, 64);
                s2acc[k] += __shfl_xor(s2acc[k], m, 64);
            }
        }
        if (l15 == 0) {
#pragma unroll
            for (int j = 0; j < 4; j++)
#pragma unroll
                for (int k = 0; k < 4; k++) {
                    int col = wn * 64 + j * 16 + quad * 4 + k;
                    st[wm * 512 + col] = sacc[j * 4 + k];
                    st[wm * 512 + 256 + col] = s2acc[j * 4 + k];
                }
        }
        __syncthreads();
        int t = threadIdx.x;
        pstats[(size_t)blockIdx.x * 512 + t] = st[t] + st[512 + t];
    }
}

// ---------------- layer-0 aggregation on xsc (8-deep batch) ----------------

__global__ __launch_bounds__(256) void agg_x_k(const unsigned short* __restrict__ xsc,
                                               const int* __restrict__ esrc,
                                               const int* __restrict__ row_start,
                                               const float* __restrict__ isd,
                                               unsigned short* __restrict__ out, int n) {
    int half = threadIdx.x >> 5;
    int sub = threadIdx.x & 31;
    int i = blockIdx.x * 8 + half;
    if (i >= n) return;
    int beg = row_start[i], end = row_start[i + 1];
    int c = sub * 4;
    float acc[4] = {0.f, 0.f, 0.f, 0.f};
    addbf4(acc, *(const ushort4*)&xsc[(size_t)i * 128 + c]);   // self
    int e = beg;
    for (; e + 7 < end; e += 8) {
        int s[8];
        ushort4 u[8];
#pragma unroll
        for (int k = 0; k < 8; k++) s[k] = esrc[e + k];
#pragma unroll
        for (int k = 0; k < 8; k++) u[k] = *(const ushort4*)&xsc[(size_t)s[k] * 128 + c];
#pragma unroll
        for (int k = 0; k < 8; k++) addbf4(acc, u[k]);
    }
    for (; e + 1 < end; e += 2) {
        int s0 = esrc[e], s1 = esrc[e + 1];
        ushort4 a = *(const ushort4*)&xsc[(size_t)s0 * 128 + c];
        ushort4 b = *(const ushort4*)&xsc[(size_t)s1 * 128 + c];
        addbf4(acc, a);
        addbf4(acc, b);
    }
    if (e < end)
        addbf4(acc, *(const ushort4*)&xsc[(size_t)esrc[e] * 128 + c]);
    float si = isd[i];
    ushort4 o;
    o.x = f2bf(si * acc[0]); o.y = f2bf(si * acc[1]);
    o.z = f2bf(si * acc[2]); o.w = f2bf(si * acc[3]);
    *(ushort4*)&out[(size_t)i * 128 + c] = o;
}

// ---------------- layers 1,2 aggregation + BN partials (8-deep batch) ----------------

__global__ __launch_bounds__(256) void agg_h_k(const unsigned short* __restrict__ hws,
                                               const int* __restrict__ esrc,
                                               const int* __restrict__ row_start,
                                               const float* __restrict__ isd,
                                               const float* __restrict__ bias,
                                               unsigned short* __restrict__ out,
                                               float* __restrict__ pbuf, int n) {
    __shared__ float ls[2048];
    int t = threadIdx.x;
    int half = t >> 5;
    int sub = t & 31;
    int c = sub * 8;
    int i = blockIdx.x * 8 + half;

    float o[8] = {0.f, 0.f, 0.f, 0.f, 0.f, 0.f, 0.f, 0.f};
    if (i < n) {
        int beg = row_start[i], end = row_start[i + 1];
        float acc[8] = {0.f, 0.f, 0.f, 0.f, 0.f, 0.f, 0.f, 0.f};
        addbf8(acc, *(const uint4*)&hws[(size_t)i * DH + c]);   // self
        int e = beg;
        for (; e + 7 < end; e += 8) {
            int s[8];
            uint4 u[8];
#pragma unroll
            for (int k = 0; k < 8; k++) s[k] = esrc[e + k];
#pragma unroll
            for (int k = 0; k < 8; k++) u[k] = *(const uint4*)&hws[(size_t)s[k] * DH + c];
#pragma unroll
            for (int k = 0; k < 8; k++) addbf8(acc, u[k]);
        }
        for (; e + 1 < end; e += 2) {
            int s0 = esrc[e], s1 = esrc[e + 1];
            uint4 a = *(const uint4*)&hws[(size_t)s0 * DH + c];
            uint4 b = *(const uint4*)&hws[(size_t)s1 * DH + c];
            addbf8(acc, a);
            addbf8(acc, b);
        }
        if (e < end)
            addbf8(acc, *(const uint4*)&hws[(size_t)esrc[e] * DH + c]);
        float si = isd[i];
        float4 b0 = *(const float4*)&bias[c];
        float4 b1 = *(const float4*)&bias[c + 4];
        o[0] = si * acc[0] + b0.x; o[1] = si * acc[1] + b0.y;
        o[2] = si * acc[2] + b0.z; o[3] = si * acc[3] + b0.w;
        o[4] = si * acc[4] + b1.x; o[5] = si * acc[5] + b1.y;
        o[6] = si * acc[6] + b1.z; o[7] = si * acc[7] + b1.w;
        unsigned short ob[8];
#pragma unroll
        for (int k = 0; k < 8; k++) ob[k] = f2bf(o[k]);
        *(uint4*)&out[(size_t)i * DH + c] = *(const uint4*)ob;
    }
    *(float4*)&ls[half * 256 + c]     = make_float4(o[0], o[1], o[2], o[3]);
    *(float4*)&ls[half * 256 + c + 4] = make_float4(o[4], o[5], o[6], o[7]);
    __syncthreads();
    float s = 0.f, s2 = 0.f;
#pragma unroll
    for (int h = 0; h < 8; h++) {
        float v = ls[h * 256 + t];
        s += v;
        s2 += v * v;
    }
    pbuf[(size_t)blockIdx.x * 512 + t] = s;
    pbuf[(size_t)blockIdx.x * 512 + 256 + t] = s2;
}

// fused BN reduce + finalize: 64 blocks; each writes its partial, last-arriving block
// (device-scope flag) folds the 64 partials and emits scale/shift.
__global__ __launch_bounds__(256) void bn_redfin_k(const float* __restrict__ pin, int nb,
                                                   float* __restrict__ pmid,
                                                   int* __restrict__ flag,
                                                   const float* __restrict__ g,
                                                   const float* __restrict__ b,
                                                   float* __restrict__ ss, float inv_n) {
    int t = threadIdx.x;
    float s = 0.f, s2 = 0.f;
    for (int r = blockIdx.x; r < nb; r += 64) {
        s += pin[(size_t)r * 512 + t];
        s2 += pin[(size_t)r * 512 + 256 + t];
    }
    pmid[(size_t)blockIdx.x * 512 + t] = s;
    pmid[(size_t)blockIdx.x * 512 + 256 + t] = s2;
    __threadfence();
    __syncthreads();
    __shared__ int lastsh;
    if (t == 0) lastsh = (atomicAdd(flag, 1) == 63) ? 1 : 0;
    __syncthreads();
    if (lastsh) {
        __threadfence();
        float S = 0.f, S2 = 0.f;
        for (int r = 0; r < 64; r++) {
            S += pmid[(size_t)r * 512 + t];
            S2 += pmid[(size_t)r * 512 + 256 + t];
        }
        float mu = S * inv_n;
        float var = S2 * inv_n - mu * mu;
        float sc = g[t] * rsqrtf(var + EPSV);
        ss[t] = sc;
        ss[DH + t] = b[t] - mu * sc;
    }
}

// ---------------- launch ----------------

extern "C" void kernel_launch(void* const* d_in, const int* in_sizes, int n_in,
                              void* d_out, int out_size, void* d_ws, size_t ws_size,
                              hipStream_t stream) {
    const float* x = (const float*)d_in[0];
    const int* eidx = (const int*)d_in[1];       // int64 in ref -> int32 on device
    const float* conv_w0 = (const float*)d_in[3];
    const float* conv_b0 = (const float*)d_in[4];
    const float* conv_w1 = (const float*)d_in[5];
    const float* conv_b1 = (const float*)d_in[6];
    const float* conv_w2 = (const float*)d_in[7];
    const float* conv_b2 = (const float*)d_in[8];
    const float* bn_g0 = (const float*)d_in[9];
    const float* bn_b0 = (const float*)d_in[10];
    const float* bn_g1 = (const float*)d_in[11];
    const float* bn_b1 = (const float*)d_in[12];
    const float* bn_g2 = (const float*)d_in[13];
    const float* bn_b2 = (const float*)d_in[14];
    const float* proj_w = (const float*)d_in[15];
    const float* proj_b = (const float*)d_in[16];
    const float* lin_w0 = (const float*)d_in[17];
    const float* lin_b0 = (const float*)d_in[18];
    const float* lin_w1 = (const float*)d_in[19];
    const float* lin_b1 = (const float*)d_in[20];
    const float* head_w = (const float*)d_in[21];
    const float* head_b = (const float*)d_in[22];

    const int N = in_sizes[2];
    const int E = in_sizes[1] / 2;
    const int* esrc_in = eidx;
    const int* edst_in = eidx + E;

    char* ws = (char*)d_ws;
    auto alloc = [&](size_t b) -> char* {
        char* p = ws;
        ws += (b + 255) & ~(size_t)255;
        return p;
    };
    unsigned short* h1_bf = (unsigned short*)alloc((size_t)N * DH * 2);
    unsigned short* h2_bf = (unsigned short*)alloc((size_t)N * DH * 2);
    unsigned short* hw_bf = (unsigned short*)alloc((size_t)N * DH * 2);
    unsigned short* pj_bf = (unsigned short*)alloc((size_t)N * DH * 2);
    unsigned short* gcn_bf = (unsigned short*)alloc((size_t)N * DH * 2);
    unsigned short* xsc = (unsigned short*)alloc((size_t)N * 128 * 2);
    unsigned short* axs = (unsigned short*)alloc((size_t)N * 128 * 2);   // S·x ; later pbuf
    float* pbuf2 = (float*)alloc((size_t)256 * 512 * 4);
    float* pmid = (float*)alloc((size_t)64 * 512 * 4);
    unsigned short* w0t = (unsigned short*)alloc((size_t)256 * 128 * 2);
    unsigned short* pjt = (unsigned short*)alloc((size_t)256 * 128 * 2);
    unsigned short* w1t = (unsigned short*)alloc((size_t)256 * 256 * 2);
    unsigned short* w2t = (unsigned short*)alloc((size_t)256 * 256 * 2);
    unsigned short* l0t = (unsigned short*)alloc((size_t)256 * 256 * 2);
    unsigned short* l1t = (unsigned short*)alloc((size_t)256 * 256 * 2);
    int* flags = (int*)alloc(256);                  // [0]=scan [1..3]=bn layers
    int* cnt = (int*)alloc((size_t)N * 4);          // contiguous with flags for one memset
    int* row_start = (int*)alloc((size_t)(N + 1) * 4);
    int* cursor = (int*)alloc((size_t)N * 4);
    int* esrc = (int*)alloc((size_t)E * 4);
    float* isd = (float*)alloc((size_t)N * 4);
    float* sdeg = (float*)alloc((size_t)N * 4);
    float* ss = (float*)alloc(2 * DH * 4);
    int* bsum = (int*)alloc(256 * 4);

    // pbuf (agg_h BN partials, gHalf*512 floats = 12.8MB) aliases axs (dead after conv0)
    float* pbuf = (float*)axs;

    const int gE = (E + 255) / 256;
    const int gHalf = (N + 7) / 8;
    const int gScan = (N + 1023) / 1024;
    const int gGemm = 256;                       // persistent full-width blocks (1/CU)
    const int n4 = N * 128 / 4;
    const int gPrep = 1536 + (n4 + 255) / 256;
    const float inv_n = 1.0f / (float)N;

    // CSR build (one memset covers flags + cnt)
    hipMemsetAsync(flags, 0, 256 + (size_t)N * 4, stream);
    count_edges_k<<<gE, 256, 0, stream>>>(edst_in, cnt, E, N);
    scan_all_k<<<gScan, 256, 0, stream>>>(cnt, bsum, &flags[0], row_start, cursor,
                                          isd, sdeg, N, gScan, E);
    scatter_edges_k<<<gE, 256, 0, stream>>>(esrc_in, edst_in, cursor, esrc, E, N);

    // weights + xsc = isd*x (bf16), one launch
    prep_k<<<gPrep, 256, 0, stream>>>(conv_w0, proj_w, conv_w1, conv_w2, lin_w0, lin_w1,
                                      w0t, pjt, w1t, w2t, l0t, l1t, x, isd, xsc, n4);

    // ---- layer 0 ----
    agg_x_k<<<gHalf, 256, 0, stream>>>(xsc, esrc, row_start, isd, axs, N);
    // proj: (xsc @ pjt) * sdeg + proj_b
    gemm_bf_k<128, true, false, true, false, false, false, true, false, false>
        <<<gGemm, 512, 0, stream>>>(xsc, pjt, proj_b, sdeg, pj_bf, N,
                                    nullptr, nullptr, nullptr, nullptr, nullptr, nullptr, nullptr);
    // conv0 GEMM with fused BN stats
    gemm_bf_k<128, true, false, false, false, true, false, true, false, false>
        <<<gGemm, 512, 0, stream>>>(axs, w0t, conv_b0, nullptr, gcn_bf, N,
                                    nullptr, nullptr, nullptr, pbuf2, nullptr, nullptr, nullptr);
    bn_redfin_k<<<64, 256, 0, stream>>>(pbuf2, gGemm, pmid, &flags[1], bn_g0, bn_b0, ss, inv_n);

    // ---- layer 1: gemm with fused BN+gelu+residual A-stage (h1 = gelu(bn(gcn0))+pj) ----
    gemm_bf_k<256, false, false, false, true, false, false, false, true, true>
        <<<gGemm, 512, 0, stream>>>(gcn_bf, w1t, nullptr, isd, hw_bf, N,
                                    nullptr, nullptr, nullptr, nullptr, pj_bf, ss, h1_bf);
    agg_h_k<<<gHalf, 256, 0, stream>>>(hw_bf, esrc, row_start, isd, conv_b1, gcn_bf, pbuf, N);
    bn_redfin_k<<<64, 256, 0, stream>>>(pbuf, gHalf, pmid, &flags[2], bn_g1, bn_b1, ss, inv_n);

    // ---- layer 2: h2 = gelu(bn(gcn1))+h1 fused into gemm A-stage ----
    gemm_bf_k<256, false, false, false, true, false, false, false, true, true>
        <<<gGemm, 512, 0, stream>>>(gcn_bf, w2t, nullptr, isd, hw_bf, N,
                                    nullptr, nullptr, nullptr, nullptr, h1_bf, ss, h2_bf);
    agg_h_k<<<gHalf, 256, 0, stream>>>(hw_bf, esrc, row_start, isd, conv_b2, gcn_bf, pbuf, N);
    bn_redfin_k<<<64, 256, 0, stream>>>(pbuf, gHalf, pmid, &flags[3], bn_g2, bn_b2, ss, inv_n);

    // ---- MLP: lin0 with fused h3 = gelu(bn(gcn2))+h2 A-stage (h3 not materialized) ----
    gemm_bf_k<256, true, true, false, false, false, false, false, true, false>
        <<<gGemm, 512, 0, stream>>>(gcn_bf, l0t, lin_b0, nullptr, h1_bf, N,
                                    nullptr, nullptr, nullptr, nullptr, h2_bf, ss, nullptr);
    // lin1 + head fused (LDS combine, non-atomic store -> no d_out memset)
    gemm_bf_k<256, true, true, false, false, false, true, false, false, false>
        <<<gGemm, 512, 0, stream>>>(h1_bf, l1t, lin_b1, nullptr, nullptr, N,
                                    head_w, head_b, (float*)d_out, nullptr, nullptr, nullptr, nullptr);
}